// Round 2
// baseline (218.982 us; speedup 1.0000x reference)
//
#include <hip/hip_runtime.h>
#include <hip/hip_bf16.h>

#define DEVI __device__ __forceinline__

typedef __attribute__((ext_vector_type(4))) float f32x4;
typedef __attribute__((ext_vector_type(8))) short bf16x8;

// Problem sizes
#define BB 4
#define SS 2048
#define DD 1024
#define MTOK (BB*SS)   // 8192

// Workspace layout (bytes)
#define OFF_XB  0ull
#define OFF_WB  (OFF_XB + (size_t)MTOK*DD*2)        // x bf16: 16 MB
#define OFF_Q   (OFF_WB + (size_t)3*DD*DD*2)        // W stacked bf16: 6 MB
#define OFF_K   (OFF_Q  + (size_t)MTOK*DD*2)
#define OFF_VT  (OFF_K  + (size_t)MTOK*DD*2)
#define OFF_P   (OFF_VT + (size_t)MTOK*DD*2)
#define OFF_LP  (OFF_P  + (size_t)BB*SS*SS*2)       // P bf16: 33.5 MB
#define OFF_L   (OFF_LP + (size_t)BB*16*2*SS*4)     // Lpart f32 [b][kt][wn][q]: 1 MB
#define WS_NEED (OFF_L  + (size_t)BB*SS*4)          // ~108 MB

DEVI void gload16(const __hip_bfloat16* g, __hip_bfloat16* l) {
  __builtin_amdgcn_global_load_lds(
      (const __attribute__((address_space(1))) unsigned int*)(const void*)g,
      (__attribute__((address_space(3))) unsigned int*)(void*)l, 16, 0, 0);
}

// Stage a 128x32 bf16 tile (row-major, row stride ldg) into LDS linear [128][32].
DEVI void stage_tile(const __hip_bfloat16* __restrict__ gsrc, int ldg,
                     __hip_bfloat16* lds, int tid) {
  int w = tid >> 6, lane = tid & 63;
  int r = lane >> 2, kk = (lane & 3) * 8;
#pragma unroll
  for (int i = 0; i < 2; i++) {
    int c = w * 2 + i;  // chunk: 16 rows, 1024 B — wave-uniform LDS base
    gload16(gsrc + (size_t)(c * 16 + r) * ldg + kk, lds + c * 512);
  }
}

// One BK=32 K-step: 4x4 fragment grid per wave (wave covers 64x64).
DEVI void kstep(const __hip_bfloat16* lsA, const __hip_bfloat16* lsB,
                int wm, int wn, int lr, int lg, f32x4 acc[4][4]) {
  bf16x8 af[4], bfr[4];
#pragma unroll
  for (int mi = 0; mi < 4; mi++)
    af[mi] = *reinterpret_cast<const bf16x8*>(lsA + (wm * 64 + mi * 16 + lr) * 32 + lg * 8);
#pragma unroll
  for (int ni = 0; ni < 4; ni++)
    bfr[ni] = *reinterpret_cast<const bf16x8*>(lsB + (wn * 64 + ni * 16 + lr) * 32 + lg * 8);
#pragma unroll
  for (int mi = 0; mi < 4; mi++)
#pragma unroll
    for (int ni = 0; ni < 4; ni++)
      acc[mi][ni] = __builtin_amdgcn_mfma_f32_16x16x32_bf16(af[mi], bfr[ni], acc[mi][ni], 0, 0, 0);
}

__global__ void cast_f32_bf16(const float* __restrict__ src,
                              __hip_bfloat16* __restrict__ dst, int n) {
  int i = (blockIdx.x * blockDim.x + threadIdx.x) * 4;
  if (i >= n) return;
  float4 v = *reinterpret_cast<const float4*>(src + i);
  __hip_bfloat16 h[4] = {__float2bfloat16(v.x), __float2bfloat16(v.y),
                         __float2bfloat16(v.z), __float2bfloat16(v.w)};
  *reinterpret_cast<uint2*>(dst + i) = *reinterpret_cast<const uint2*>(h);
}

// QKV projection: A = xb [8192][1024], B = Wb stacked [3072][1024] (B^T layout).
// Q,K stored row-major [tok][1024]; V stored transposed Vt[b][d][s].
__launch_bounds__(256)
__global__ void gemm_qkv(const __hip_bfloat16* __restrict__ xb,
                         const __hip_bfloat16* __restrict__ Wb,
                         __hip_bfloat16* __restrict__ Q,
                         __hip_bfloat16* __restrict__ Kb,
                         __hip_bfloat16* __restrict__ Vt) {
  __shared__ __hip_bfloat16 lsA[128 * 32], lsB[128 * 32];
  int nt = blockIdx.x, mt = blockIdx.y;
  int tid = threadIdx.x, w = tid >> 6, lane = tid & 63, lr = lane & 15, lg = lane >> 4;
  int wm = w >> 1, wn = w & 1;
  f32x4 acc[4][4];
  f32x4 zero = {0.f, 0.f, 0.f, 0.f};
#pragma unroll
  for (int i = 0; i < 4; i++)
#pragma unroll
    for (int j = 0; j < 4; j++) acc[i][j] = zero;

  const __hip_bfloat16* Ab = xb + (size_t)mt * 128 * 1024;
  const __hip_bfloat16* Bm = Wb + (size_t)nt * 128 * 1024;
  for (int k0 = 0; k0 < 1024; k0 += 32) {
    stage_tile(Ab + k0, 1024, lsA, tid);
    stage_tile(Bm + k0, 1024, lsB, tid);
    __syncthreads();
    kstep(lsA, lsB, wm, wn, lr, lg, acc);
    __syncthreads();
  }

  int which = nt >> 3;                  // 0=Q, 1=K, 2=V
  int ncol0 = (nt & 7) * 128 + wn * 64; // col within the 1024-wide output
  int mrow0 = mt * 128 + wm * 64;       // token index
#pragma unroll
  for (int mi = 0; mi < 4; mi++)
#pragma unroll
    for (int ni = 0; ni < 4; ni++)
#pragma unroll
      for (int r = 0; r < 4; r++) {
        int row = mrow0 + mi * 16 + lg * 4 + r;
        int col = ncol0 + ni * 16 + lr;
        __hip_bfloat16 hv = __float2bfloat16(acc[mi][ni][r]);
        if (which == 0)      Q[(size_t)row * 1024 + col] = hv;
        else if (which == 1) Kb[(size_t)row * 1024 + col] = hv;
        else {
          int b = row >> 11, s = row & 2047;
          Vt[((size_t)b * 1024 + col) * 2048 + s] = hv;
        }
      }
}

// Scores: P_unnorm[b][q][k] = exp(scale * q.k) (causal-masked), bf16.
// Per-(b,ktile,wn-strip) row partial sums go to separate Lpart slots (no race).
__launch_bounds__(256)
__global__ void qk_scores(const __hip_bfloat16* __restrict__ Q,
                          const __hip_bfloat16* __restrict__ Kb,
                          __hip_bfloat16* __restrict__ P,
                          float* __restrict__ Lpart) {
  int kt = blockIdx.x, qt = blockIdx.y, b = blockIdx.z;
  if (kt > qt) return;
  __shared__ __hip_bfloat16 lsA[128 * 32], lsB[128 * 32];
  int tid = threadIdx.x, w = tid >> 6, lane = tid & 63, lr = lane & 15, lg = lane >> 4;
  int wm = w >> 1, wn = w & 1;
  f32x4 acc[4][4];
  f32x4 zero = {0.f, 0.f, 0.f, 0.f};
#pragma unroll
  for (int i = 0; i < 4; i++)
#pragma unroll
    for (int j = 0; j < 4; j++) acc[i][j] = zero;

  const __hip_bfloat16* Ab = Q + ((size_t)b * 2048 + qt * 128) * 1024;
  const __hip_bfloat16* Bm = Kb + ((size_t)b * 2048 + kt * 128) * 1024;
  for (int k0 = 0; k0 < 1024; k0 += 32) {
    stage_tile(Ab + k0, 1024, lsA, tid);
    stage_tile(Bm + k0, 1024, lsB, tid);
    __syncthreads();
    kstep(lsA, lsB, wm, wn, lr, lg, acc);
    __syncthreads();
  }

  const float scale = 0.03125f;  // 1/sqrt(1024)
  float part[4][4];
#pragma unroll
  for (int i = 0; i < 4; i++)
#pragma unroll
    for (int r = 0; r < 4; r++) part[i][r] = 0.f;

  __hip_bfloat16* Pb = P + (size_t)b * 2048 * 2048;
#pragma unroll
  for (int mi = 0; mi < 4; mi++)
#pragma unroll
    for (int ni = 0; ni < 4; ni++)
#pragma unroll
      for (int r = 0; r < 4; r++) {
        int q = qt * 128 + wm * 64 + mi * 16 + lg * 4 + r;
        int k = kt * 128 + wn * 64 + ni * 16 + lr;
        float p = (k <= q) ? __expf(acc[mi][ni][r] * scale) : 0.f;
        __hip_bfloat16 hv = __float2bfloat16(p);
        Pb[(size_t)q * 2048 + k] = hv;
        part[mi][r] += __bfloat162float(hv);  // sum the bf16-rounded value
      }

  // reduce partial row sums across the 16-lane column group
#pragma unroll
  for (int mi = 0; mi < 4; mi++)
#pragma unroll
    for (int r = 0; r < 4; r++) {
      float s = part[mi][r];
      s += __shfl_xor(s, 1); s += __shfl_xor(s, 2);
      s += __shfl_xor(s, 4); s += __shfl_xor(s, 8);
      part[mi][r] = s;
    }
  if (lr < 4) {
#pragma unroll
    for (int mi = 0; mi < 4; mi++) {
      int q = qt * 128 + wm * 64 + mi * 16 + lg * 4 + lr;
      // slot per (b, kt, wn): the two column-wave strips must not collide
      Lpart[(((size_t)b * 16 + kt) * 2 + wn) * 2048 + q] = part[mi][lr];
    }
  }
}

__global__ void reduce_L(const float* __restrict__ Lpart, float* __restrict__ L) {
  int i = blockIdx.x * 256 + threadIdx.x;  // [0, 8192)
  int b = i >> 11, q = i & 2047;
  int nkt = (q >> 7) + 1;
  float s = 0.f;
  for (int kt = 0; kt < nkt; kt++) {
    s += Lpart[(((size_t)b * 16 + kt) * 2 + 0) * 2048 + q];
    s += Lpart[(((size_t)b * 16 + kt) * 2 + 1) * 2048 + q];
  }
  L[i] = s;
}

// out[b][q][d] = (P_b @ V_b)[q][d] / L[b][q]; A = P (row-major), B = Vt (B^T layout).
__launch_bounds__(256)
__global__ void pv_out(const __hip_bfloat16* __restrict__ P,
                       const __hip_bfloat16* __restrict__ Vt,
                       const float* __restrict__ L,
                       float* __restrict__ out) {
  int dt = blockIdx.x, qt = blockIdx.y, b = blockIdx.z;
  __shared__ __hip_bfloat16 lsA[128 * 32], lsB[128 * 32];
  int tid = threadIdx.x, w = tid >> 6, lane = tid & 63, lr = lane & 15, lg = lane >> 4;
  int wm = w >> 1, wn = w & 1;
  f32x4 acc[4][4];
  f32x4 zero = {0.f, 0.f, 0.f, 0.f};
#pragma unroll
  for (int i = 0; i < 4; i++)
#pragma unroll
    for (int j = 0; j < 4; j++) acc[i][j] = zero;

  const __hip_bfloat16* Ab = P + (size_t)b * 2048 * 2048 + (size_t)qt * 128 * 2048;
  const __hip_bfloat16* Bm = Vt + (size_t)b * 1024 * 2048 + (size_t)dt * 128 * 2048;
  int kend = (qt + 1) * 128;  // causal: only k-tiles <= q-tile
  for (int k0 = 0; k0 < kend; k0 += 32) {
    stage_tile(Ab + k0, 2048, lsA, tid);
    stage_tile(Bm + k0, 2048, lsB, tid);
    __syncthreads();
    kstep(lsA, lsB, wm, wn, lr, lg, acc);
    __syncthreads();
  }

#pragma unroll
  for (int mi = 0; mi < 4; mi++)
#pragma unroll
    for (int r = 0; r < 4; r++) {
      int q = qt * 128 + wm * 64 + mi * 16 + lg * 4 + r;  // batch-local row
      float inv = 1.f / L[(size_t)b * 2048 + q];
#pragma unroll
      for (int ni = 0; ni < 4; ni++) {
        int d = dt * 128 + wn * 64 + ni * 16 + lr;
        out[((size_t)b * 2048 + q) * 1024 + d] = acc[mi][ni][r] * inv;
      }
    }
}

extern "C" void kernel_launch(void* const* d_in, const int* in_sizes, int n_in,
                              void* d_out, int out_size, void* d_ws, size_t ws_size,
                              hipStream_t stream) {
  const float* x  = (const float*)d_in[0];
  const float* Wq = (const float*)d_in[1];
  const float* Wk = (const float*)d_in[2];
  const float* Wv = (const float*)d_in[3];
  float* out = (float*)d_out;
  char* ws = (char*)d_ws;
  if (ws_size < WS_NEED) return;  // workspace too small — will fail validation visibly

  __hip_bfloat16* xb = (__hip_bfloat16*)(ws + OFF_XB);
  __hip_bfloat16* Wb = (__hip_bfloat16*)(ws + OFF_WB);
  __hip_bfloat16* Q  = (__hip_bfloat16*)(ws + OFF_Q);
  __hip_bfloat16* Kb = (__hip_bfloat16*)(ws + OFF_K);
  __hip_bfloat16* Vt = (__hip_bfloat16*)(ws + OFF_VT);
  __hip_bfloat16* P  = (__hip_bfloat16*)(ws + OFF_P);
  float* Lpart = (float*)(ws + OFF_LP);
  float* L     = (float*)(ws + OFF_L);

  cast_f32_bf16<<<8192, 256, 0, stream>>>(x, xb, MTOK * DD);
  cast_f32_bf16<<<1024, 256, 0, stream>>>(Wq, Wb, DD * DD);
  cast_f32_bf16<<<1024, 256, 0, stream>>>(Wk, Wb + (size_t)DD * DD, DD * DD);
  cast_f32_bf16<<<1024, 256, 0, stream>>>(Wv, Wb + (size_t)2 * DD * DD, DD * DD);

  gemm_qkv<<<dim3(24, 64), 256, 0, stream>>>(xb, Wb, Q, Kb, Vt);
  qk_scores<<<dim3(16, 16, 4), 256, 0, stream>>>(Q, Kb, P, Lpart);
  reduce_L<<<32, 256, 0, stream>>>(Lpart, L);
  pv_out<<<dim3(8, 16, 4), 256, 0, stream>>>(P, Vt, L, out);
}

// Round 3
// 192.386 us; speedup vs baseline: 1.1382x; 1.1382x over previous
//
#include <hip/hip_runtime.h>
#include <hip/hip_bf16.h>

#define DEVI __device__ __forceinline__

typedef __attribute__((ext_vector_type(4))) float f32x4;
typedef __attribute__((ext_vector_type(8))) short bf16x8;

// Problem sizes
#define BB 4
#define SS 2048
#define DD 1024
#define MTOK (BB*SS)   // 8192

// Workspace layout (bytes)
#define OFF_XB  0ull
#define OFF_WB  (OFF_XB + (size_t)MTOK*DD*2)        // x bf16: 16 MB
#define OFF_Q   (OFF_WB + (size_t)3*DD*DD*2)        // W stacked bf16: 6 MB
#define OFF_K   (OFF_Q  + (size_t)MTOK*DD*2)
#define OFF_VT  (OFF_K  + (size_t)MTOK*DD*2)
#define OFF_P   (OFF_VT + (size_t)MTOK*DD*2)
#define OFF_LP  (OFF_P  + (size_t)BB*SS*SS*2)       // P bf16: 33.5 MB
#define OFF_L   (OFF_LP + (size_t)BB*16*2*SS*4)     // Lpart f32 [b][kt][wn][q]: 1 MB
#define WS_NEED (OFF_L  + (size_t)BB*SS*4)          // ~108 MB

DEVI void gload16(const __hip_bfloat16* g, __hip_bfloat16* l) {
  __builtin_amdgcn_global_load_lds(
      (const __attribute__((address_space(1))) unsigned int*)(const void*)g,
      (__attribute__((address_space(3))) unsigned int*)(void*)l, 16, 0, 0);
}

// ---- pipelined 128x128 GEMM core, BK=32, 3 LDS buffers, swizzled layout ----
// LDS tile: [128 rows][4 slots of 16B]; global slot s stored at lds slot
// s ^ ((row>>1)&3)  (2-way bank aliasing = free). Staged via pre-swizzled
// global source addresses (global_load_lds dest is linear: base + lane*16B).

// Stage one 128x32 bf16 tile (2 loads/thread, 256 threads).
DEVI void stage32(const __hip_bfloat16* __restrict__ g, int ldg,
                  __hip_bfloat16* dst, int tid) {
  int w = tid >> 6, l = tid & 63;
  int r = l >> 2, slot = (l & 3) ^ ((l >> 3) & 3);  // pre-swizzled source slot
#pragma unroll
  for (int i = 0; i < 2; i++) {
    int c = w * 2 + i;  // 16-row chunk, wave-uniform LDS base
    gload16(g + (size_t)(c * 16 + r) * ldg + slot * 8, dst + c * 512);
  }
}

// Read one bf16x8 fragment (row, k-slot lg) honoring the swizzle.
DEVI bf16x8 fragread(const __hip_bfloat16* base, int row, int lg) {
  int slot = lg ^ ((row >> 1) & 3);
  return *reinterpret_cast<const bf16x8*>(base + row * 32 + slot * 8);
}

// A: [M][lda] row-major panel (128 rows); B: [N][ldb] B^T-layout panel (128 rows).
// NT = K/32 k-tiles (NT >= 2). lds must hold 3*8192 bf16 (48 KB).
DEVI void gemm_core(const __hip_bfloat16* __restrict__ A, int lda,
                    const __hip_bfloat16* __restrict__ B, int ldb,
                    int NT, __hip_bfloat16* lds, int tid, f32x4 acc[4][4]) {
  int lane = tid & 63, lr = lane & 15, lg = lane >> 4;
  int w = tid >> 6, wm = w >> 1, wn = w & 1;

  // prologue: stage tiles 0 and 1 (8 loads/thread total? no: 4/thread... 2A+2B per tile)
  stage32(A, lda, lds + 0 * 8192, tid);
  stage32(B, ldb, lds + 0 * 8192 + 4096, tid);
  stage32(A + 32, lda, lds + 1 * 8192, tid);
  stage32(B + 32, ldb, lds + 1 * 8192 + 4096, tid);

  for (int t = 0; t < NT; ++t) {
    // tile t's 4 loads are the oldest; tile t+1's 4 may stay in flight (T4)
    if (t + 1 < NT) asm volatile("s_waitcnt vmcnt(4)" ::: "memory");
    else            asm volatile("s_waitcnt vmcnt(0)" ::: "memory");
    asm volatile("s_barrier" ::: "memory");  // all waves' tile-t loads landed

    const __hip_bfloat16* cA = lds + (t % 3) * 8192;
    const __hip_bfloat16* cB = cA + 4096;
    __hip_bfloat16* nA = lds + ((t + 2) % 3) * 8192;
    bool st = (t + 2) < NT;

    bf16x8 bfr[4], af[4];
#pragma unroll
    for (int ni = 0; ni < 4; ni++) bfr[ni] = fragread(cB, wn * 64 + ni * 16 + lr, lg);
#pragma unroll
    for (int mi = 0; mi < 2; mi++) af[mi] = fragread(cA, wm * 64 + mi * 16 + lr, lg);
    if (st) stage32(A + (size_t)(t + 2) * 32, lda, nA, tid);  // issue early (T14/T3)
    __builtin_amdgcn_s_setprio(1);
#pragma unroll
    for (int mi = 0; mi < 2; mi++)
#pragma unroll
      for (int ni = 0; ni < 4; ni++)
        acc[mi][ni] = __builtin_amdgcn_mfma_f32_16x16x32_bf16(af[mi], bfr[ni], acc[mi][ni], 0, 0, 0);
    __builtin_amdgcn_s_setprio(0);

#pragma unroll
    for (int mi = 2; mi < 4; mi++) af[mi] = fragread(cA, wm * 64 + mi * 16 + lr, lg);
    if (st) stage32(B + (size_t)(t + 2) * 32, ldb, nA + 4096, tid);
    __builtin_amdgcn_s_setprio(1);
#pragma unroll
    for (int mi = 2; mi < 4; mi++)
#pragma unroll
      for (int ni = 0; ni < 4; ni++)
        acc[mi][ni] = __builtin_amdgcn_mfma_f32_16x16x32_bf16(af[mi], bfr[ni], acc[mi][ni], 0, 0, 0);
    __builtin_amdgcn_s_setprio(0);

    // force my tile-t ds_reads complete before I pass the next barrier, so
    // other waves' stages into this buffer (2 tiles ahead) cannot clobber
    // in-flight reads. (rule #18: sched_barrier pins the wait.)
    asm volatile("s_waitcnt lgkmcnt(0)" ::: "memory");
    __builtin_amdgcn_sched_barrier(0);
  }
}

__global__ void cast_f32_bf16(const float* __restrict__ src,
                              __hip_bfloat16* __restrict__ dst, int n) {
  int i = (blockIdx.x * blockDim.x + threadIdx.x) * 4;
  if (i >= n) return;
  float4 v = *reinterpret_cast<const float4*>(src + i);
  __hip_bfloat16 h[4] = {__float2bfloat16(v.x), __float2bfloat16(v.y),
                         __float2bfloat16(v.z), __float2bfloat16(v.w)};
  *reinterpret_cast<uint2*>(dst + i) = *reinterpret_cast<const uint2*>(h);
}

// QKV projection: A = xb [8192][1024], B = Wb stacked [3072][1024] (B^T layout).
// Q,K stored row-major [tok][1024]; V stored transposed Vt[b][d][s].
__launch_bounds__(256, 3)
__global__ void gemm_qkv(const __hip_bfloat16* __restrict__ xb,
                         const __hip_bfloat16* __restrict__ Wb,
                         __hip_bfloat16* __restrict__ Q,
                         __hip_bfloat16* __restrict__ Kb,
                         __hip_bfloat16* __restrict__ Vt) {
  __shared__ __hip_bfloat16 lds[3 * 8192];
  int nt = blockIdx.x, mt = blockIdx.y;
  int tid = threadIdx.x, lane = tid & 63, lr = lane & 15, lg = lane >> 4;
  int w = tid >> 6, wm = w >> 1, wn = w & 1;
  f32x4 acc[4][4];
  f32x4 zero = {0.f, 0.f, 0.f, 0.f};
#pragma unroll
  for (int i = 0; i < 4; i++)
#pragma unroll
    for (int j = 0; j < 4; j++) acc[i][j] = zero;

  gemm_core(xb + (size_t)mt * 128 * 1024, 1024,
            Wb + (size_t)nt * 128 * 1024, 1024, 32, lds, tid, acc);

  int which = nt >> 3;                  // 0=Q, 1=K, 2=V
  int ncol0 = (nt & 7) * 128 + wn * 64;
  int mrow0 = mt * 128 + wm * 64;
#pragma unroll
  for (int mi = 0; mi < 4; mi++)
#pragma unroll
    for (int ni = 0; ni < 4; ni++)
#pragma unroll
      for (int r = 0; r < 4; r++) {
        int row = mrow0 + mi * 16 + lg * 4 + r;
        int col = ncol0 + ni * 16 + lr;
        __hip_bfloat16 hv = __float2bfloat16(acc[mi][ni][r]);
        if (which == 0)      Q[(size_t)row * 1024 + col] = hv;
        else if (which == 1) Kb[(size_t)row * 1024 + col] = hv;
        else {
          int b = row >> 11, s = row & 2047;
          Vt[((size_t)b * 1024 + col) * 2048 + s] = hv;
        }
      }
}

// Scores: P_unnorm[b][q][k] = exp(scale * q.k) (causal-masked), bf16.
// Per-(b,ktile,wn-strip) row partial sums go to separate Lpart slots (no race).
__launch_bounds__(256, 3)
__global__ void qk_scores(const __hip_bfloat16* __restrict__ Q,
                          const __hip_bfloat16* __restrict__ Kb,
                          __hip_bfloat16* __restrict__ P,
                          float* __restrict__ Lpart) {
  int kt = blockIdx.x, qt = blockIdx.y, b = blockIdx.z;
  if (kt > qt) return;
  __shared__ __hip_bfloat16 lds[3 * 8192];
  int tid = threadIdx.x, lane = tid & 63, lr = lane & 15, lg = lane >> 4;
  int w = tid >> 6, wm = w >> 1, wn = w & 1;
  f32x4 acc[4][4];
  f32x4 zero = {0.f, 0.f, 0.f, 0.f};
#pragma unroll
  for (int i = 0; i < 4; i++)
#pragma unroll
    for (int j = 0; j < 4; j++) acc[i][j] = zero;

  gemm_core(Q + ((size_t)b * 2048 + qt * 128) * 1024, 1024,
            Kb + ((size_t)b * 2048 + kt * 128) * 1024, 1024, 32, lds, tid, acc);

  const float scale = 0.03125f;  // 1/sqrt(1024)
  float part[4][4];
#pragma unroll
  for (int i = 0; i < 4; i++)
#pragma unroll
    for (int r = 0; r < 4; r++) part[i][r] = 0.f;

  __hip_bfloat16* Pb = P + (size_t)b * 2048 * 2048;
#pragma unroll
  for (int mi = 0; mi < 4; mi++)
#pragma unroll
    for (int ni = 0; ni < 4; ni++)
#pragma unroll
      for (int r = 0; r < 4; r++) {
        int q = qt * 128 + wm * 64 + mi * 16 + lg * 4 + r;
        int k = kt * 128 + wn * 64 + ni * 16 + lr;
        float p = (k <= q) ? __expf(acc[mi][ni][r] * scale) : 0.f;
        __hip_bfloat16 hv = __float2bfloat16(p);
        Pb[(size_t)q * 2048 + k] = hv;
        part[mi][r] += __bfloat162float(hv);  // sum the bf16-rounded value
      }

#pragma unroll
  for (int mi = 0; mi < 4; mi++)
#pragma unroll
    for (int r = 0; r < 4; r++) {
      float s = part[mi][r];
      s += __shfl_xor(s, 1); s += __shfl_xor(s, 2);
      s += __shfl_xor(s, 4); s += __shfl_xor(s, 8);
      part[mi][r] = s;
    }
  if (lr < 4) {
#pragma unroll
    for (int mi = 0; mi < 4; mi++) {
      int q = qt * 128 + wm * 64 + mi * 16 + lg * 4 + lr;
      Lpart[(((size_t)b * 16 + kt) * 2 + wn) * 2048 + q] = part[mi][lr];
    }
  }
}

__global__ void reduce_L(const float* __restrict__ Lpart, float* __restrict__ L) {
  int i = blockIdx.x * 256 + threadIdx.x;  // [0, 8192)
  int b = i >> 11, q = i & 2047;
  int nkt = (q >> 7) + 1;
  float s = 0.f;
  for (int kt = 0; kt < nkt; kt++) {
    s += Lpart[(((size_t)b * 16 + kt) * 2 + 0) * 2048 + q];
    s += Lpart[(((size_t)b * 16 + kt) * 2 + 1) * 2048 + q];
  }
  L[i] = s;
}

// out[b][q][d] = (P_b @ V_b)[q][d] / L[b][q]; A = P (row-major), B = Vt (B^T layout).
__launch_bounds__(256, 3)
__global__ void pv_out(const __hip_bfloat16* __restrict__ P,
                       const __hip_bfloat16* __restrict__ Vt,
                       const float* __restrict__ L,
                       float* __restrict__ out) {
  int dt = blockIdx.x, qt = blockIdx.y, b = blockIdx.z;
  __shared__ __hip_bfloat16 lds[3 * 8192];
  int tid = threadIdx.x, lane = tid & 63, lr = lane & 15, lg = lane >> 4;
  int w = tid >> 6, wm = w >> 1, wn = w & 1;
  f32x4 acc[4][4];
  f32x4 zero = {0.f, 0.f, 0.f, 0.f};
#pragma unroll
  for (int i = 0; i < 4; i++)
#pragma unroll
    for (int j = 0; j < 4; j++) acc[i][j] = zero;

  gemm_core(P + (size_t)b * 2048 * 2048 + (size_t)qt * 128 * 2048, 2048,
            Vt + (size_t)b * 1024 * 2048 + (size_t)dt * 128 * 2048, 2048,
            (qt + 1) * 4, lds, tid, acc);

#pragma unroll
  for (int mi = 0; mi < 4; mi++)
#pragma unroll
    for (int r = 0; r < 4; r++) {
      int q = qt * 128 + wm * 64 + mi * 16 + lg * 4 + r;  // batch-local row
      float inv = 1.f / L[(size_t)b * 2048 + q];
#pragma unroll
      for (int ni = 0; ni < 4; ni++) {
        int d = dt * 128 + wn * 64 + ni * 16 + lr;
        out[((size_t)b * 2048 + q) * 1024 + d] = acc[mi][ni][r] * inv;
      }
    }
}

extern "C" void kernel_launch(void* const* d_in, const int* in_sizes, int n_in,
                              void* d_out, int out_size, void* d_ws, size_t ws_size,
                              hipStream_t stream) {
  const float* x  = (const float*)d_in[0];
  const float* Wq = (const float*)d_in[1];
  const float* Wk = (const float*)d_in[2];
  const float* Wv = (const float*)d_in[3];
  float* out = (float*)d_out;
  char* ws = (char*)d_ws;
  if (ws_size < WS_NEED) return;

  __hip_bfloat16* xb = (__hip_bfloat16*)(ws + OFF_XB);
  __hip_bfloat16* Wb = (__hip_bfloat16*)(ws + OFF_WB);
  __hip_bfloat16* Q  = (__hip_bfloat16*)(ws + OFF_Q);
  __hip_bfloat16* Kb = (__hip_bfloat16*)(ws + OFF_K);
  __hip_bfloat16* Vt = (__hip_bfloat16*)(ws + OFF_VT);
  __hip_bfloat16* P  = (__hip_bfloat16*)(ws + OFF_P);
  float* Lpart = (float*)(ws + OFF_LP);
  float* L     = (float*)(ws + OFF_L);

  cast_f32_bf16<<<8192, 256, 0, stream>>>(x, xb, MTOK * DD);
  cast_f32_bf16<<<1024, 256, 0, stream>>>(Wq, Wb, DD * DD);
  cast_f32_bf16<<<1024, 256, 0, stream>>>(Wk, Wb + (size_t)DD * DD, DD * DD);
  cast_f32_bf16<<<1024, 256, 0, stream>>>(Wv, Wb + (size_t)2 * DD * DD, DD * DD);

  gemm_qkv<<<dim3(24, 64), 256, 0, stream>>>(xb, Wb, Q, Kb, Vt);
  qk_scores<<<dim3(16, 16, 4), 256, 0, stream>>>(Q, Kb, P, Lpart);
  reduce_L<<<32, 256, 0, stream>>>(Lpart, L);
  pv_out<<<dim3(8, 16, 4), 256, 0, stream>>>(P, Vt, L, out);
}